// Round 2
// baseline (308.194 us; speedup 1.0000x reference)
//
#include <hip/hip_runtime.h>

#define TT 2048
#define DD 1024
#define NHH 8
#define DKK 128
#define SCALE 0.08838834764831845f
#define NEGV -1e30f

typedef __attribute__((ext_vector_type(8))) short short8;
typedef __attribute__((ext_vector_type(4))) short short4v;
typedef __attribute__((ext_vector_type(4))) float float4v;
typedef __attribute__((ext_vector_type(4))) int   int4v;
typedef __attribute__((ext_vector_type(2))) unsigned uint2v;

__device__ __forceinline__ short f2bf(float f) {
  union { float f; unsigned u; } v; v.f = f;
  unsigned r = v.u + 0x7FFFu + ((v.u >> 16) & 1u);
  return (short)(r >> 16);
}
__device__ __forceinline__ unsigned pack2bf(float a, float b) {
  return (unsigned)(unsigned short)f2bf(a) | ((unsigned)(unsigned short)f2bf(b) << 16);
}

// ---- transpose + cast: x (B, D, T) f32 -> xt (B*T, D) bf16 ----
// grid (T/32, D/32, B), block 256
__global__ __launch_bounds__(256) void k_xt(const float* __restrict__ x,
                                            short* __restrict__ xt) {
  __shared__ float tile[32][33];
  int b = blockIdx.z, d0 = blockIdx.y << 5, t0 = blockIdx.x << 5;
  int tx = threadIdx.x & 31, ty = threadIdx.x >> 5;
  const float* xp = x + ((size_t)b * DD + d0) * TT + t0;
#pragma unroll
  for (int yy = 0; yy < 32; yy += 8)
    tile[ty + yy][tx] = xp[(size_t)(ty + yy) * TT + tx];
  __syncthreads();
  short* op = xt + ((size_t)b * TT + t0) * DD + d0;
#pragma unroll
  for (int yy = 0; yy < 32; yy += 8)
    op[(size_t)(ty + yy) * DD + tx] = f2bf(tile[tx][ty + yy]);
}

// ---- cast f32 -> bf16, vectorized x4; n4 = n/4 ----
__global__ void k_cast(const float* __restrict__ w, short* __restrict__ o, int n4) {
  int i = blockIdx.x * 256 + threadIdx.x;
  if (i < n4) {
    float4v v = ((const float4v*)w)[i];
    short4v s;
#pragma unroll
    for (int j = 0; j < 4; ++j) s[j] = f2bf(v[j]);
    ((short4v*)o)[i] = s;
  }
}

// ---- GEMM: C = A(M x 1024) * Bt(N x 1024)^T, A/Bt bf16 k-contiguous ----
// EPI 0: C bf16 row-major (ldc=1024)   [Q projection]
// EPI 1: C f32 at out[(b*1024 + m)*2048 + (n & 2047)], b = n>>11  [out proj]
// grid (M/128, N/128), block 256 (4 waves, 2x2 of 64x64)
template <int EPI>
__global__ __launch_bounds__(256) void k_gemm(const short* __restrict__ A,
                                              const short* __restrict__ Bt,
                                              void* __restrict__ Cout) {
  __shared__ short As[128][72];
  __shared__ short Bs[128][72];
  const int K = 1024;
  int tm = blockIdx.x * 128, tn = blockIdx.y * 128;
  int tid = threadIdx.x, lane = tid & 63, w = tid >> 6;
  int wm = (w >> 1) * 64, wn = (w & 1) * 64;
  int g = lane >> 4;

  float4v acc[4][4];
#pragma unroll
  for (int mt = 0; mt < 4; ++mt)
#pragma unroll
    for (int nt = 0; nt < 4; ++nt) acc[mt][nt] = (float4v){0.f, 0.f, 0.f, 0.f};

  for (int k0 = 0; k0 < K; k0 += 64) {
    __syncthreads();
#pragma unroll
    for (int c = 0; c < 4; ++c) {
      int chunk = tid + 256 * c;      // 0..1023
      int row = chunk >> 3, col8 = chunk & 7;
      int4v va = *(const int4v*)(A + (size_t)(tm + row) * K + k0 + col8 * 8);
      *(int4v*)(&As[row][col8 * 8]) = va;
      int4v vb = *(const int4v*)(Bt + (size_t)(tn + row) * K + k0 + col8 * 8);
      *(int4v*)(&Bs[row][col8 * 8]) = vb;
    }
    __syncthreads();
#pragma unroll
    for (int k4 = 0; k4 < 2; ++k4) {
      int kk = k4 * 32 + g * 8;
      short8 af[4], bfr[4];
#pragma unroll
      for (int mt = 0; mt < 4; ++mt)
        af[mt] = *(const short8*)(&As[wm + mt * 16 + (lane & 15)][kk]);
#pragma unroll
      for (int nt = 0; nt < 4; ++nt)
        bfr[nt] = *(const short8*)(&Bs[wn + nt * 16 + (lane & 15)][kk]);
#pragma unroll
      for (int mt = 0; mt < 4; ++mt)
#pragma unroll
        for (int nt = 0; nt < 4; ++nt)
          acc[mt][nt] = __builtin_amdgcn_mfma_f32_16x16x32_bf16(af[mt], bfr[nt],
                                                                acc[mt][nt], 0, 0, 0);
    }
  }

#pragma unroll
  for (int mt = 0; mt < 4; ++mt)
#pragma unroll
    for (int nt = 0; nt < 4; ++nt)
#pragma unroll
      for (int r = 0; r < 4; ++r) {
        int m = tm + wm + mt * 16 + g * 4 + r;
        int n = tn + wn + nt * 16 + (lane & 15);
        float v = acc[mt][nt][r];
        if (EPI == 0) {
          ((short*)Cout)[(size_t)m * 1024 + n] = f2bf(v);
        } else {
          int b = n >> 11, t = n & 2047;
          ((float*)Cout)[((size_t)b * 1024 + m) * 2048 + t] = v;
        }
      }
}

// ---- fused masked self-attention (Q=K=V=qh), flash-style ----
// grid (T/64, B*NH), block 256 (4 waves x 16 q-rows). KVBLK=64.
__global__ __launch_bounds__(256) void k_attn(const short* __restrict__ q,
                                              const float* __restrict__ mask,
                                              short* __restrict__ ctx) {
  __shared__ short Ks[64][136];       // [key][d], d = 128 (+8 pad)  <-- FIXED (was [64][72])
  __shared__ short Vt[128][72];       // [d][key], key = 64 (+8 pad)
  __shared__ unsigned PL[4][16][36];  // per-wave P bf16-pair words, pad 4
  __shared__ float smask[64];

  int qt = blockIdx.x;
  int bh = blockIdx.y;
  int b = bh >> 3, h = bh & 7;
  int tid = threadIdx.x, lane = tid & 63, w = tid >> 6;
  int g = lane >> 4, ql = lane & 15;

  int qrow = qt * 64 + w * 16 + ql;   // this lane's q-row (S^T/softmax view)
  const short* qp = q + ((size_t)(b * TT + qrow)) * DD + h * DKK;
  short8 qf[4];
#pragma unroll
  for (int ks = 0; ks < 4; ++ks)
    qf[ks] = *(const short8*)(qp + ks * 32 + g * 8);
  float rm = mask[(size_t)b * TT + qrow];

  float m_run = -__builtin_inff();
  float l_run = 0.f;
  float4v o[8];
#pragma unroll
  for (int nt = 0; nt < 8; ++nt) o[nt] = (float4v){0.f, 0.f, 0.f, 0.f};

  for (int kt = 0; kt < 32; ++kt) {
    int kb0 = kt * 64;
    __syncthreads();
    // ---- stage K-tile (row-major) + V-transposed + mask ----
#pragma unroll
    for (int ps = 0; ps < 2; ++ps) {
      int u = tid + 256 * ps;         // 0..511
      int oc = u & 15;                // d-octet
      int p = u >> 4;                 // key-pair
      const short* kp = q + ((size_t)(b * TT + kb0 + 2 * p)) * DD + h * DKK + oc * 8;
      short8 va = *(const short8*)(kp);
      short8 vb = *(const short8*)(kp + DD);
      *(short8*)(&Ks[2 * p][oc * 8]) = va;
      *(short8*)(&Ks[2 * p + 1][oc * 8]) = vb;
#pragma unroll
      for (int j = 0; j < 8; ++j) {
        unsigned pk = (unsigned)(unsigned short)va[j] |
                      ((unsigned)(unsigned short)vb[j] << 16);
        *(unsigned*)(&Vt[oc * 8 + j][2 * p]) = pk;
      }
    }
    if (tid < 64) smask[tid] = mask[(size_t)b * TT + kb0 + tid];
    __syncthreads();

    // ---- S^T = K * Q^T (m=key, n=q) ----
    float4v st[4];
#pragma unroll
    for (int mt = 0; mt < 4; ++mt) {
      float4v a = (float4v){0.f, 0.f, 0.f, 0.f};
#pragma unroll
      for (int ks = 0; ks < 4; ++ks) {
        short8 kf = *(const short8*)(&Ks[mt * 16 + ql][ks * 32 + g * 8]);
        a = __builtin_amdgcn_mfma_f32_16x16x32_bf16(kf, qf[ks], a, 0, 0, 0);
      }
      st[mt] = a;
    }

    // ---- masked logits + online softmax (per lane: 16 keys of own q) ----
    float lg[4][4];
    float rowmax = -__builtin_inff();
#pragma unroll
    for (int mt = 0; mt < 4; ++mt) {
      float4v sm = *(const float4v*)(&smask[mt * 16 + g * 4]);
#pragma unroll
      for (int r = 0; r < 4; ++r) {
        float v = (sm[r] != 0.f) ? st[mt][r] * SCALE : NEGV;
        v *= rm;
        lg[mt][r] = v;
        rowmax = fmaxf(rowmax, v);
      }
    }
    rowmax = fmaxf(rowmax, __shfl_xor(rowmax, 16));
    rowmax = fmaxf(rowmax, __shfl_xor(rowmax, 32));
    float m_new = fmaxf(m_run, rowmax);
    float fac = __expf(m_run - m_new);
    float tsum = 0.f;
    float pv[4][4];
#pragma unroll
    for (int mt = 0; mt < 4; ++mt)
#pragma unroll
      for (int r = 0; r < 4; ++r) {
        float p = __expf(lg[mt][r] - m_new);
        pv[mt][r] = p;
        tsum += p;
      }
    tsum += __shfl_xor(tsum, 16);
    tsum += __shfl_xor(tsum, 32);
    l_run = l_run * fac + tsum;
    m_run = m_new;

    // ---- rescale O (O rows are q' = g*4+r; factor lives in lane q') ----
    float fs[4];
#pragma unroll
    for (int r = 0; r < 4; ++r) fs[r] = __shfl(fac, g * 4 + r);
#pragma unroll
    for (int nt = 0; nt < 8; ++nt)
#pragma unroll
      for (int r = 0; r < 4; ++r) o[nt][r] *= fs[r];

    // ---- P -> bf16 A-frags via per-wave LDS redistribution ----
#pragma unroll
    for (int mt = 0; mt < 4; ++mt) {
      unsigned w0 = pack2bf(pv[mt][0], pv[mt][1]);
      unsigned w1 = pack2bf(pv[mt][2], pv[mt][3]);
      uint2v pr; pr[0] = w0; pr[1] = w1;
      *(uint2v*)(&PL[w][ql][mt * 8 + g * 2]) = pr;
    }
    short8 pfrag[2];
#pragma unroll
    for (int ks = 0; ks < 2; ++ks)
      pfrag[ks] = *(const short8*)(&PL[w][ql][ks * 16 + g * 4]);

    // ---- O += P * V ----
#pragma unroll
    for (int nt = 0; nt < 8; ++nt) {
#pragma unroll
      for (int ks = 0; ks < 2; ++ks) {
        short8 vf = *(const short8*)(&Vt[nt * 16 + ql][ks * 32 + g * 8]);
        o[nt] = __builtin_amdgcn_mfma_f32_16x16x32_bf16(pfrag[ks], vf, o[nt], 0, 0, 0);
      }
    }
  }

  // ---- normalize and write ctx (bf16, (B*T, D) with D-index h*128+d) ----
  float il[4];
#pragma unroll
  for (int r = 0; r < 4; ++r) {
    float lr = __shfl(l_run, g * 4 + r);
    il[r] = 1.0f / lr;
  }
  int qbase = qt * 64 + w * 16;
#pragma unroll
  for (int nt = 0; nt < 8; ++nt)
#pragma unroll
    for (int r = 0; r < 4; ++r) {
      int qq = qbase + g * 4 + r;
      int d = nt * 16 + ql;
      ctx[((size_t)(b * TT + qq)) * DD + h * DKK + d] = f2bf(o[nt][r] * il[r]);
    }
}

extern "C" void kernel_launch(void* const* d_in, const int* in_sizes, int n_in,
                              void* d_out, int out_size, void* d_ws, size_t ws_size,
                              hipStream_t stream) {
  const float* x    = (const float*)d_in[0];
  const float* mask = (const float*)d_in[1];
  const float* Wq   = (const float*)d_in[2];
  const float* Wo   = (const float*)d_in[3];
  char* ws = (char*)d_ws;
  short* xt  = (short*)(ws);                              // 16 MB
  short* wqb = (short*)(ws + (size_t)16 * 1024 * 1024);   // 2 MB
  short* wob = (short*)(ws + (size_t)18 * 1024 * 1024);   // 2 MB
  short* qb  = (short*)(ws + (size_t)20 * 1024 * 1024);   // 16 MB
  short* ctx = (short*)(ws + (size_t)36 * 1024 * 1024);   // 16 MB

  k_xt<<<dim3(64, 32, 4), 256, 0, stream>>>(x, xt);
  k_cast<<<1024, 256, 0, stream>>>(Wq, wqb, 262144);
  k_cast<<<1024, 256, 0, stream>>>(Wo, wob, 262144);
  k_gemm<0><<<dim3(64, 8), 256, 0, stream>>>(xt, wqb, qb);
  k_attn<<<dim3(32, 32), 256, 0, stream>>>(qb, mask, ctx);
  k_gemm<1><<<dim3(8, 64), 256, 0, stream>>>(wob, ctx, d_out);
}

// Round 5
// 223.787 us; speedup vs baseline: 1.3772x; 1.3772x over previous
//
#include <hip/hip_runtime.h>

#define TT 2048
#define DD 1024
#define NHH 8
#define DKK 128
// softmax in log2 domain: v_exp_f32 is natively 2^x
#define SCALE2 0.1275174724f          /* (1/sqrt(128)) * log2(e) */
#define NEG2  -1.4426950409e30f       /* -1e30 * log2(e) */

typedef __attribute__((ext_vector_type(8))) short short8;
typedef __attribute__((ext_vector_type(4))) short short4v;
typedef __attribute__((ext_vector_type(4))) float float4v;
typedef __attribute__((ext_vector_type(4))) int   int4v;
typedef __attribute__((ext_vector_type(2))) unsigned uint2v;

__device__ __forceinline__ short f2bf(float f) {
  union { float f; unsigned u; } v; v.f = f;
  unsigned r = v.u + 0x7FFFu + ((v.u >> 16) & 1u);
  return (short)(r >> 16);
}
__device__ __forceinline__ unsigned pack2bf(float a, float b) {
  return (unsigned)(unsigned short)f2bf(a) | ((unsigned)(unsigned short)f2bf(b) << 16);
}

// ---- transpose + cast: x (B, D, T) f32 -> xt (B*T, D) bf16 ----
__global__ __launch_bounds__(256) void k_xt(const float* __restrict__ x,
                                            short* __restrict__ xt) {
  __shared__ float tile[32][33];
  int b = blockIdx.z, d0 = blockIdx.y << 5, t0 = blockIdx.x << 5;
  int tx = threadIdx.x & 31, ty = threadIdx.x >> 5;
  const float* xp = x + ((size_t)b * DD + d0) * TT + t0;
#pragma unroll
  for (int yy = 0; yy < 32; yy += 8)
    tile[ty + yy][tx] = xp[(size_t)(ty + yy) * TT + tx];
  __syncthreads();
  short* op = xt + ((size_t)b * TT + t0) * DD + d0;
#pragma unroll
  for (int yy = 0; yy < 32; yy += 8)
    op[(size_t)(ty + yy) * DD + tx] = f2bf(tile[tx][ty + yy]);
}

__global__ void k_cast(const float* __restrict__ w, short* __restrict__ o, int n4) {
  int i = blockIdx.x * 256 + threadIdx.x;
  if (i < n4) {
    float4v v = ((const float4v*)w)[i];
    short4v s;
#pragma unroll
    for (int j = 0; j < 4; ++j) s[j] = f2bf(v[j]);
    ((short4v*)o)[i] = s;
  }
}

// ---- transpose Q: qb (B*T, 1024) bf16 -> qhT (B*1024 rows of n=h*128+d, T) bf16 ----
// grid (T/64, 1024/64, B), block 256
__global__ __launch_bounds__(256) void k_qt(const short* __restrict__ qb,
                                            short* __restrict__ qhT) {
  __shared__ short tile[64][65];
  int b = blockIdx.z, n0 = blockIdx.y << 6, t0 = blockIdx.x << 6;
  int tx = threadIdx.x & 63, ty = threadIdx.x >> 6;
  const short* ip = qb + ((size_t)(b * TT + t0)) * DD + n0;
#pragma unroll
  for (int yy = 0; yy < 64; yy += 4)
    tile[ty + yy][tx] = ip[(size_t)(ty + yy) * DD + tx];
  __syncthreads();
  short* op = qhT + ((size_t)(b * DD + n0)) * TT + t0;
#pragma unroll
  for (int yy = 0; yy < 64; yy += 4)
    op[(size_t)(ty + yy) * TT + tx] = tile[tx][ty + yy];
}

// ---- GEMM: C = A(M x 1024) * Bt(N x 1024)^T ----
template <int EPI>
__global__ __launch_bounds__(256) void k_gemm(const short* __restrict__ A,
                                              const short* __restrict__ Bt,
                                              void* __restrict__ Cout) {
  __shared__ short As[128][72];
  __shared__ short Bs[128][72];
  const int K = 1024;
  int tm = blockIdx.x * 128, tn = blockIdx.y * 128;
  int tid = threadIdx.x, lane = tid & 63, w = tid >> 6;
  int wm = (w >> 1) * 64, wn = (w & 1) * 64;
  int g = lane >> 4;

  float4v acc[4][4];
#pragma unroll
  for (int mt = 0; mt < 4; ++mt)
#pragma unroll
    for (int nt = 0; nt < 4; ++nt) acc[mt][nt] = (float4v){0.f, 0.f, 0.f, 0.f};

  for (int k0 = 0; k0 < K; k0 += 64) {
    __syncthreads();
#pragma unroll
    for (int c = 0; c < 4; ++c) {
      int chunk = tid + 256 * c;
      int row = chunk >> 3, col8 = chunk & 7;
      int4v va = *(const int4v*)(A + (size_t)(tm + row) * K + k0 + col8 * 8);
      *(int4v*)(&As[row][col8 * 8]) = va;
      int4v vb = *(const int4v*)(Bt + (size_t)(tn + row) * K + k0 + col8 * 8);
      *(int4v*)(&Bs[row][col8 * 8]) = vb;
    }
    __syncthreads();
#pragma unroll
    for (int k4 = 0; k4 < 2; ++k4) {
      int kk = k4 * 32 + g * 8;
      short8 af[4], bfr[4];
#pragma unroll
      for (int mt = 0; mt < 4; ++mt)
        af[mt] = *(const short8*)(&As[wm + mt * 16 + (lane & 15)][kk]);
#pragma unroll
      for (int nt = 0; nt < 4; ++nt)
        bfr[nt] = *(const short8*)(&Bs[wn + nt * 16 + (lane & 15)][kk]);
#pragma unroll
      for (int mt = 0; mt < 4; ++mt)
#pragma unroll
        for (int nt = 0; nt < 4; ++nt)
          acc[mt][nt] = __builtin_amdgcn_mfma_f32_16x16x32_bf16(af[mt], bfr[nt],
                                                                acc[mt][nt], 0, 0, 0);
    }
  }

#pragma unroll
  for (int mt = 0; mt < 4; ++mt)
#pragma unroll
    for (int nt = 0; nt < 4; ++nt)
#pragma unroll
      for (int r = 0; r < 4; ++r) {
        int m = tm + wm + mt * 16 + g * 4 + r;
        int n = tn + wn + nt * 16 + (lane & 15);
        float v = acc[mt][nt][r];
        if (EPI == 0) {
          ((short*)Cout)[(size_t)m * 1024 + n] = f2bf(v);
        } else {
          int b = n >> 11, t = n & 2047;
          ((float*)Cout)[((size_t)b * 1024 + m) * 2048 + t] = v;
        }
      }
}

// ---- fused masked self-attention (Q=K=V=qh), flash-style ----
// grid (T/64, B*NH), block 256 (4 waves x 16 q-rows). KVBLK=64.
__global__ __launch_bounds__(256) void k_attn(const short* __restrict__ q,
                                              const short* __restrict__ qhT,
                                              const float* __restrict__ mask,
                                              short* __restrict__ ctx) {
  __shared__ short Ks[64][136];       // [key][d=128 +8 pad]
  __shared__ short Vt[128][72];       // [d][key=64 +8 pad] — staged from qhT, NO transpose
  __shared__ unsigned PL[4][16][36];  // per-wave P bf16-pair words
  __shared__ float smask[64];

  int qt = blockIdx.x, bh = blockIdx.y;
  int b = bh >> 3, h = bh & 7;
  int tid = threadIdx.x, lane = tid & 63, w = tid >> 6;
  int g = lane >> 4, ql = lane & 15;

  int qrow = qt * 64 + w * 16 + ql;
  const short* qp = q + ((size_t)(b * TT + qrow)) * DD + h * DKK;
  short8 qf[4];
#pragma unroll
  for (int ks = 0; ks < 4; ++ks)
    qf[ks] = *(const short8*)(qp + ks * 32 + g * 8);
  float rm = mask[(size_t)b * TT + qrow];

  // K staging map: oc = d-octet (0..15), r2 = key-pair (0..15)
  int oc = tid & 15, r2 = tid >> 4;
  const short* kbase_g = q + ((size_t)b * TT) * DD + h * DKK + oc * 8;
  // V^T staging map: 4 passes, idx = p*256+tid: d = idx>>3, ko = idx&7
  const short* vbase_g = qhT + ((size_t)(b * DD + h * DKK)) * TT;
  int vd[4], vko[4];
#pragma unroll
  for (int p = 0; p < 4; ++p) {
    int idx = p * 256 + tid;
    vd[p] = idx >> 3;
    vko[p] = idx & 7;
  }

  // prologue: load tile 0 into regs
  short8 va[2], vb[2], vv[4];
#pragma unroll
  for (int ps = 0; ps < 2; ++ps) {
    const short* kp = kbase_g + (size_t)(2 * r2 + 32 * ps) * DD;
    va[ps] = *(const short8*)(kp);
    vb[ps] = *(const short8*)(kp + DD);
  }
#pragma unroll
  for (int p = 0; p < 4; ++p)
    vv[p] = *(const short8*)(vbase_g + (size_t)vd[p] * TT + vko[p] * 8);
  float mreg = (tid < 64) ? mask[(size_t)b * TT + tid] : 0.f;

  float m_run = -__builtin_inff();
  float l_run = 0.f;
  float4v o[8];
#pragma unroll
  for (int nt = 0; nt < 8; ++nt) o[nt] = (float4v){0.f, 0.f, 0.f, 0.f};

  for (int kt = 0; kt < 32; ++kt) {
    __syncthreads();
#pragma unroll
    for (int ps = 0; ps < 2; ++ps) {
      *(short8*)(&Ks[2 * r2 + 32 * ps][oc * 8]) = va[ps];
      *(short8*)(&Ks[2 * r2 + 1 + 32 * ps][oc * 8]) = vb[ps];
    }
#pragma unroll
    for (int p = 0; p < 4; ++p)
      *(short8*)(&Vt[vd[p]][vko[p] * 8]) = vv[p];
    if (tid < 64) smask[tid] = mreg;
    __syncthreads();

    // prefetch next tile into regs (hides HBM/L2 latency under compute)
    if (kt < 31) {
      int kb0n = (kt + 1) * 64;
      const short* kpn = kbase_g + (size_t)kb0n * DD;
#pragma unroll
      for (int ps = 0; ps < 2; ++ps) {
        const short* kp = kpn + (size_t)(2 * r2 + 32 * ps) * DD;
        va[ps] = *(const short8*)(kp);
        vb[ps] = *(const short8*)(kp + DD);
      }
#pragma unroll
      for (int p = 0; p < 4; ++p)
        vv[p] = *(const short8*)(vbase_g + (size_t)vd[p] * TT + kb0n + vko[p] * 8);
      if (tid < 64) mreg = mask[(size_t)b * TT + kb0n + tid];
    }

    // ---- S^T = K * Q^T (m=key, n=q) ----
    float4v st[4];
    __builtin_amdgcn_s_setprio(1);
#pragma unroll
    for (int mt = 0; mt < 4; ++mt) {
      float4v a = (float4v){0.f, 0.f, 0.f, 0.f};
#pragma unroll
      for (int ks = 0; ks < 4; ++ks) {
        short8 kf = *(const short8*)(&Ks[mt * 16 + ql][ks * 32 + g * 8]);
        a = __builtin_amdgcn_mfma_f32_16x16x32_bf16(kf, qf[ks], a, 0, 0, 0);
      }
      st[mt] = a;
    }
    __builtin_amdgcn_s_setprio(0);

    // ---- masked logits (log2 domain) + online softmax ----
    float lg[4][4];
    float rowmax = -__builtin_inff();
#pragma unroll
    for (int mt = 0; mt < 4; ++mt) {
      float4v sm = *(const float4v*)(&smask[mt * 16 + g * 4]);
#pragma unroll
      for (int r = 0; r < 4; ++r) {
        float v = (sm[r] != 0.f) ? st[mt][r] * SCALE2 : NEG2;
        v *= rm;
        lg[mt][r] = v;
        rowmax = fmaxf(rowmax, v);
      }
    }
    rowmax = fmaxf(rowmax, __shfl_xor(rowmax, 16));
    rowmax = fmaxf(rowmax, __shfl_xor(rowmax, 32));
    float m_new = fmaxf(m_run, rowmax);
    float fac = __builtin_amdgcn_exp2f(m_run - m_new);
    float tsum = 0.f;
#pragma unroll
    for (int mt = 0; mt < 4; ++mt)
#pragma unroll
      for (int r = 0; r < 4; ++r) {
        float p = __builtin_amdgcn_exp2f(lg[mt][r] - m_new);
        lg[mt][r] = p;
        tsum += p;
      }
    tsum += __shfl_xor(tsum, 16);
    tsum += __shfl_xor(tsum, 32);
    l_run = l_run * fac + tsum;
    m_run = m_new;

    // ---- rescale O ----
    float fs[4];
#pragma unroll
    for (int r = 0; r < 4; ++r) fs[r] = __shfl(fac, g * 4 + r);
#pragma unroll
    for (int nt = 0; nt < 8; ++nt)
#pragma unroll
      for (int r = 0; r < 4; ++r) o[nt][r] *= fs[r];

    // ---- P -> bf16 A-frags via per-wave LDS redistribution ----
#pragma unroll
    for (int mt = 0; mt < 4; ++mt) {
      uint2v pr;
      pr[0] = pack2bf(lg[mt][0], lg[mt][1]);
      pr[1] = pack2bf(lg[mt][2], lg[mt][3]);
      *(uint2v*)(&PL[w][ql][mt * 8 + g * 2]) = pr;
    }
    short8 pfrag[2];
#pragma unroll
    for (int ks = 0; ks < 2; ++ks)
      pfrag[ks] = *(const short8*)(&PL[w][ql][ks * 16 + g * 4]);

    // ---- O += P * V ----
    __builtin_amdgcn_s_setprio(1);
#pragma unroll
    for (int nt = 0; nt < 8; ++nt) {
#pragma unroll
      for (int ks = 0; ks < 2; ++ks) {
        short8 vf = *(const short8*)(&Vt[nt * 16 + ql][ks * 32 + g * 8]);
        o[nt] = __builtin_amdgcn_mfma_f32_16x16x32_bf16(pfrag[ks], vf, o[nt], 0, 0, 0);
      }
    }
    __builtin_amdgcn_s_setprio(0);
  }

  // ---- normalize and write ctx ----
  float il[4];
#pragma unroll
  for (int r = 0; r < 4; ++r) {
    float lr = __shfl(l_run, g * 4 + r);
    il[r] = 1.0f / lr;
  }
  int qbase = qt * 64 + w * 16;
#pragma unroll
  for (int nt = 0; nt < 8; ++nt)
#pragma unroll
    for (int r = 0; r < 4; ++r) {
      int qq = qbase + g * 4 + r;
      int d = nt * 16 + ql;
      ctx[((size_t)(b * TT + qq)) * DD + h * DKK + d] = f2bf(o[nt][r] * il[r]);
    }
}

extern "C" void kernel_launch(void* const* d_in, const int* in_sizes, int n_in,
                              void* d_out, int out_size, void* d_ws, size_t ws_size,
                              hipStream_t stream) {
  const float* x    = (const float*)d_in[0];
  const float* mask = (const float*)d_in[1];
  const float* Wq   = (const float*)d_in[2];
  const float* Wo   = (const float*)d_in[3];
  char* ws = (char*)d_ws;
  short* xt  = (short*)(ws);                              // 16 MB (reused as qhT)
  short* wqb = (short*)(ws + (size_t)16 * 1024 * 1024);
  short* wob = (short*)(ws + (size_t)18 * 1024 * 1024);
  short* qb  = (short*)(ws + (size_t)20 * 1024 * 1024);
  short* ctx = (short*)(ws + (size_t)36 * 1024 * 1024);
  short* qhT = xt;   // xt dead after k_gemm<0>; k_qt runs after it

  k_xt<<<dim3(64, 32, 4), 256, 0, stream>>>(x, xt);
  k_cast<<<1024, 256, 0, stream>>>(Wq, wqb, 262144);
  k_cast<<<1024, 256, 0, stream>>>(Wo, wob, 262144);
  k_gemm<0><<<dim3(64, 8), 256, 0, stream>>>(xt, wqb, qb);
  k_qt<<<dim3(32, 16, 4), 256, 0, stream>>>(qb, qhT);
  k_attn<<<dim3(32, 32), 256, 0, stream>>>(qb, qhT, mask, ctx);
  k_gemm<1><<<dim3(8, 64), 256, 0, stream>>>(wob, ctx, d_out);
}

// Round 6
// 177.773 us; speedup vs baseline: 1.7336x; 1.2588x over previous
//
#include <hip/hip_runtime.h>

#define TT 2048
#define DD 1024
#define NHH 8
#define DKK 128
// softmax in log2 domain: v_exp_f32 is natively 2^x
#define SCALE2 0.1275174724f          /* (1/sqrt(128)) * log2(e) */
#define NEG2  -1.4426950409e30f       /* -1e30 * log2(e) */

typedef __attribute__((ext_vector_type(8))) short short8;
typedef __attribute__((ext_vector_type(4))) short short4v;
typedef __attribute__((ext_vector_type(4))) float float4v;
typedef __attribute__((ext_vector_type(4))) int   int4v;
typedef __attribute__((ext_vector_type(2))) unsigned uint2v;

__device__ __forceinline__ short f2bf(float f) {
  union { float f; unsigned u; } v; v.f = f;
  unsigned r = v.u + 0x7FFFu + ((v.u >> 16) & 1u);
  return (short)(r >> 16);
}
__device__ __forceinline__ unsigned cvtpk(float lo, float hi) {
  unsigned r;
  asm("v_cvt_pk_bf16_f32 %0, %1, %2" : "=v"(r) : "v"(lo), "v"(hi));
  return r;
}

// ---- transpose + cast: x (B, D, T) f32 -> xt (B*T, D) bf16 ----
__global__ __launch_bounds__(256) void k_xt(const float* __restrict__ x,
                                            short* __restrict__ xt) {
  __shared__ float tile[32][33];
  int b = blockIdx.z, d0 = blockIdx.y << 5, t0 = blockIdx.x << 5;
  int tx = threadIdx.x & 31, ty = threadIdx.x >> 5;
  const float* xp = x + ((size_t)b * DD + d0) * TT + t0;
#pragma unroll
  for (int yy = 0; yy < 32; yy += 8)
    tile[ty + yy][tx] = xp[(size_t)(ty + yy) * TT + tx];
  __syncthreads();
  short* op = xt + ((size_t)b * TT + t0) * DD + d0;
#pragma unroll
  for (int yy = 0; yy < 32; yy += 8)
    op[(size_t)(ty + yy) * DD + tx] = f2bf(tile[tx][ty + yy]);
}

__global__ void k_cast(const float* __restrict__ w, short* __restrict__ o, int n4) {
  int i = blockIdx.x * 256 + threadIdx.x;
  if (i < n4) {
    float4v v = ((const float4v*)w)[i];
    short4v s;
#pragma unroll
    for (int j = 0; j < 4; ++j) s[j] = f2bf(v[j]);
    ((short4v*)o)[i] = s;
  }
}

// ---- transpose Q: qb (B*T, 1024) bf16 -> qhT (B*1024, T) bf16 ----
__global__ __launch_bounds__(256) void k_qt(const short* __restrict__ qb,
                                            short* __restrict__ qhT) {
  __shared__ short tile[64][65];
  int b = blockIdx.z, n0 = blockIdx.y << 6, t0 = blockIdx.x << 6;
  int tx = threadIdx.x & 63, ty = threadIdx.x >> 6;
  const short* ip = qb + ((size_t)(b * TT + t0)) * DD + n0;
#pragma unroll
  for (int yy = 0; yy < 64; yy += 4)
    tile[ty + yy][tx] = ip[(size_t)(ty + yy) * DD + tx];
  __syncthreads();
  short* op = qhT + ((size_t)(b * DD + n0)) * TT + t0;
#pragma unroll
  for (int yy = 0; yy < 64; yy += 4)
    op[(size_t)(ty + yy) * TT + tx] = tile[tx][ty + yy];
}

// ---- GEMM: C = A(M x 1024) * Bt(N x 1024)^T ----
template <int EPI>
__global__ __launch_bounds__(256) void k_gemm(const short* __restrict__ A,
                                              const short* __restrict__ Bt,
                                              void* __restrict__ Cout) {
  __shared__ short As[128][72];
  __shared__ short Bs[128][72];
  const int K = 1024;
  int tm = blockIdx.x * 128, tn = blockIdx.y * 128;
  int tid = threadIdx.x, lane = tid & 63, w = tid >> 6;
  int wm = (w >> 1) * 64, wn = (w & 1) * 64;
  int g = lane >> 4;

  float4v acc[4][4];
#pragma unroll
  for (int mt = 0; mt < 4; ++mt)
#pragma unroll
    for (int nt = 0; nt < 4; ++nt) acc[mt][nt] = (float4v){0.f, 0.f, 0.f, 0.f};

  for (int k0 = 0; k0 < K; k0 += 64) {
    __syncthreads();
#pragma unroll
    for (int c = 0; c < 4; ++c) {
      int chunk = tid + 256 * c;
      int row = chunk >> 3, col8 = chunk & 7;
      int4v va = *(const int4v*)(A + (size_t)(tm + row) * K + k0 + col8 * 8);
      *(int4v*)(&As[row][col8 * 8]) = va;
      int4v vb = *(const int4v*)(Bt + (size_t)(tn + row) * K + k0 + col8 * 8);
      *(int4v*)(&Bs[row][col8 * 8]) = vb;
    }
    __syncthreads();
#pragma unroll
    for (int k4 = 0; k4 < 2; ++k4) {
      int kk = k4 * 32 + g * 8;
      short8 af[4], bfr[4];
#pragma unroll
      for (int mt = 0; mt < 4; ++mt)
        af[mt] = *(const short8*)(&As[wm + mt * 16 + (lane & 15)][kk]);
#pragma unroll
      for (int nt = 0; nt < 4; ++nt)
        bfr[nt] = *(const short8*)(&Bs[wn + nt * 16 + (lane & 15)][kk]);
#pragma unroll
      for (int mt = 0; mt < 4; ++mt)
#pragma unroll
        for (int nt = 0; nt < 4; ++nt)
          acc[mt][nt] = __builtin_amdgcn_mfma_f32_16x16x32_bf16(af[mt], bfr[nt],
                                                                acc[mt][nt], 0, 0, 0);
    }
  }

#pragma unroll
  for (int mt = 0; mt < 4; ++mt)
#pragma unroll
    for (int nt = 0; nt < 4; ++nt)
#pragma unroll
      for (int r = 0; r < 4; ++r) {
        int m = tm + wm + mt * 16 + g * 4 + r;
        int n = tn + wn + nt * 16 + (lane & 15);
        float v = acc[mt][nt][r];
        if (EPI == 0) {
          ((short*)Cout)[(size_t)m * 1024 + n] = f2bf(v);
        } else {
          int b = n >> 11, t = n & 2047;
          ((float*)Cout)[((size_t)b * 1024 + m) * 2048 + t] = v;
        }
      }
}

// ---- fused masked self-attention, flash-style ----
// grid (T/128, B*NH), block 256: 4 waves x 32 q-rows (2 column-sets of 16).
// Each K/V fragment read from LDS feeds 2 MFMAs (one per q-set).
__global__ __launch_bounds__(256, 2) void k_attn(const short* __restrict__ q,
                                                 const short* __restrict__ qhT,
                                                 const float* __restrict__ mask,
                                                 short* __restrict__ ctx) {
  __shared__ short Ks[64][136];       // [key][d=128 +8 pad]
  __shared__ short Vt[128][72];       // [d][key=64 +8 pad]
  __shared__ unsigned PL[4][16][36];  // per-wave P redistribution (reused per set)
  __shared__ float smask[64];

  int qt = blockIdx.x, bh = blockIdx.y;
  int b = bh >> 3, h = bh & 7;
  int tid = threadIdx.x, lane = tid & 63, w = tid >> 6;
  int g = lane >> 4, ql = lane & 15;

  int qrow0 = qt * 128 + w * 32 + ql;        // set s adds s*16
  short8 qf[2][4];
  float rm[2];
#pragma unroll
  for (int s = 0; s < 2; ++s) {
    const short* qp = q + ((size_t)(b * TT + qrow0 + s * 16)) * DD + h * DKK;
#pragma unroll
    for (int ks = 0; ks < 4; ++ks)
      qf[s][ks] = *(const short8*)(qp + ks * 32 + g * 8);
    rm[s] = mask[(size_t)b * TT + qrow0 + s * 16];
  }

  // K staging map: oc = d-octet (0..15), r2 = key-pair (0..15)
  int oc = tid & 15, r2 = tid >> 4;
  const short* kbase_g = q + ((size_t)b * TT) * DD + h * DKK + oc * 8;
  const short* vbase_g = qhT + ((size_t)(b * DD + h * DKK)) * TT;
  int vd[4], vko[4];
#pragma unroll
  for (int p = 0; p < 4; ++p) {
    int idx = p * 256 + tid;
    vd[p] = idx >> 3;
    vko[p] = idx & 7;
  }

  // prologue: tile 0 into regs
  short8 va[2], vb[2], vv[4];
#pragma unroll
  for (int ps = 0; ps < 2; ++ps) {
    const short* kp = kbase_g + (size_t)(2 * r2 + 32 * ps) * DD;
    va[ps] = *(const short8*)(kp);
    vb[ps] = *(const short8*)(kp + DD);
  }
#pragma unroll
  for (int p = 0; p < 4; ++p)
    vv[p] = *(const short8*)(vbase_g + (size_t)vd[p] * TT + vko[p] * 8);
  float mreg = (tid < 64) ? mask[(size_t)b * TT + tid] : 0.f;

  float m_run[2] = {-__builtin_inff(), -__builtin_inff()};
  float l_run[2] = {0.f, 0.f};
  float4v o[2][8];
#pragma unroll
  for (int s = 0; s < 2; ++s)
#pragma unroll
    for (int nt = 0; nt < 8; ++nt) o[s][nt] = (float4v){0.f, 0.f, 0.f, 0.f};

  for (int kt = 0; kt < 32; ++kt) {
    __syncthreads();
#pragma unroll
    for (int ps = 0; ps < 2; ++ps) {
      *(short8*)(&Ks[2 * r2 + 32 * ps][oc * 8]) = va[ps];
      *(short8*)(&Ks[2 * r2 + 1 + 32 * ps][oc * 8]) = vb[ps];
    }
#pragma unroll
    for (int p = 0; p < 4; ++p)
      *(short8*)(&Vt[vd[p]][vko[p] * 8]) = vv[p];
    if (tid < 64) smask[tid] = mreg;
    __syncthreads();

    // prefetch next tile into regs
    if (kt < 31) {
      int kb0n = (kt + 1) * 64;
      const short* kpn = kbase_g + (size_t)kb0n * DD;
#pragma unroll
      for (int ps = 0; ps < 2; ++ps) {
        const short* kp = kpn + (size_t)(2 * r2 + 32 * ps) * DD;
        va[ps] = *(const short8*)(kp);
        vb[ps] = *(const short8*)(kp + DD);
      }
#pragma unroll
      for (int p = 0; p < 4; ++p)
        vv[p] = *(const short8*)(vbase_g + (size_t)vd[p] * TT + kb0n + vko[p] * 8);
      if (tid < 64) mreg = mask[(size_t)b * TT + kb0n + tid];
    }

    // ---- S^T = K * Q^T for both q-sets (each kf read feeds 2 MFMAs) ----
    float4v st[2][4];
    __builtin_amdgcn_s_setprio(1);
#pragma unroll
    for (int mt = 0; mt < 4; ++mt) {
      float4v a0 = (float4v){0.f, 0.f, 0.f, 0.f};
      float4v a1 = (float4v){0.f, 0.f, 0.f, 0.f};
#pragma unroll
      for (int ks = 0; ks < 4; ++ks) {
        short8 kf = *(const short8*)(&Ks[mt * 16 + ql][ks * 32 + g * 8]);
        a0 = __builtin_amdgcn_mfma_f32_16x16x32_bf16(kf, qf[0][ks], a0, 0, 0, 0);
        a1 = __builtin_amdgcn_mfma_f32_16x16x32_bf16(kf, qf[1][ks], a1, 0, 0, 0);
      }
      st[0][mt] = a0;
      st[1][mt] = a1;
    }
    __builtin_amdgcn_s_setprio(0);

    // ---- per-set: masked logits + online softmax + P redistribution ----
    short8 pfrag[2][2];
#pragma unroll
    for (int s = 0; s < 2; ++s) {
      float lg[4][4];
      float rowmax = -__builtin_inff();
#pragma unroll
      for (int mt = 0; mt < 4; ++mt) {
        float4v sm = *(const float4v*)(&smask[mt * 16 + g * 4]);
#pragma unroll
        for (int r = 0; r < 4; ++r) {
          float v = (sm[r] != 0.f) ? st[s][mt][r] * SCALE2 : NEG2;
          v *= rm[s];
          lg[mt][r] = v;
          rowmax = fmaxf(rowmax, v);
        }
      }
      rowmax = fmaxf(rowmax, __shfl_xor(rowmax, 16));
      rowmax = fmaxf(rowmax, __shfl_xor(rowmax, 32));
      float m_new = fmaxf(m_run[s], rowmax);
      float fac = __builtin_amdgcn_exp2f(m_run[s] - m_new);
      float tsum = 0.f;
#pragma unroll
      for (int mt = 0; mt < 4; ++mt)
#pragma unroll
        for (int r = 0; r < 4; ++r) {
          float p = __builtin_amdgcn_exp2f(lg[mt][r] - m_new);
          lg[mt][r] = p;
          tsum += p;
        }
      tsum += __shfl_xor(tsum, 16);
      tsum += __shfl_xor(tsum, 32);
      l_run[s] = l_run[s] * fac + tsum;
      m_run[s] = m_new;

      float fs[4];
#pragma unroll
      for (int r = 0; r < 4; ++r) fs[r] = __shfl(fac, g * 4 + r);
#pragma unroll
      for (int nt = 0; nt < 8; ++nt)
#pragma unroll
        for (int r = 0; r < 4; ++r) o[s][nt][r] *= fs[r];

      // P -> bf16 A-frags via per-wave LDS bounce (buffer reused per set)
#pragma unroll
      for (int mt = 0; mt < 4; ++mt) {
        uint2v pr;
        pr[0] = cvtpk(lg[mt][0], lg[mt][1]);
        pr[1] = cvtpk(lg[mt][2], lg[mt][3]);
        *(uint2v*)(&PL[w][ql][mt * 8 + g * 2]) = pr;
      }
#pragma unroll
      for (int ks = 0; ks < 2; ++ks)
        pfrag[s][ks] = *(const short8*)(&PL[w][ql][ks * 16 + g * 4]);
    }

    // ---- O += P * V (each vf read feeds 2 MFMAs) ----
    __builtin_amdgcn_s_setprio(1);
#pragma unroll
    for (int nt = 0; nt < 8; ++nt) {
#pragma unroll
      for (int ks = 0; ks < 2; ++ks) {
        short8 vf = *(const short8*)(&Vt[nt * 16 + ql][ks * 32 + g * 8]);
        o[0][nt] = __builtin_amdgcn_mfma_f32_16x16x32_bf16(pfrag[0][ks], vf, o[0][nt], 0, 0, 0);
        o[1][nt] = __builtin_amdgcn_mfma_f32_16x16x32_bf16(pfrag[1][ks], vf, o[1][nt], 0, 0, 0);
      }
    }
    __builtin_amdgcn_s_setprio(0);
  }

  // ---- normalize and write ctx ----
#pragma unroll
  for (int s = 0; s < 2; ++s) {
    float il[4];
#pragma unroll
    for (int r = 0; r < 4; ++r) {
      float lr = __shfl(l_run[s], g * 4 + r);
      il[r] = 1.0f / lr;
    }
    int qbase = qt * 128 + w * 32 + s * 16;
#pragma unroll
    for (int nt = 0; nt < 8; ++nt)
#pragma unroll
      for (int r = 0; r < 4; ++r) {
        int qq = qbase + g * 4 + r;
        int d = nt * 16 + ql;
        ctx[((size_t)(b * TT + qq)) * DD + h * DKK + d] = f2bf(o[s][nt][r] * il[r]);
      }
  }
}

extern "C" void kernel_launch(void* const* d_in, const int* in_sizes, int n_in,
                              void* d_out, int out_size, void* d_ws, size_t ws_size,
                              hipStream_t stream) {
  const float* x    = (const float*)d_in[0];
  const float* mask = (const float*)d_in[1];
  const float* Wq   = (const float*)d_in[2];
  const float* Wo   = (const float*)d_in[3];
  char* ws = (char*)d_ws;
  short* xt  = (short*)(ws);                              // 16 MB (reused as qhT)
  short* wqb = (short*)(ws + (size_t)16 * 1024 * 1024);
  short* wob = (short*)(ws + (size_t)18 * 1024 * 1024);
  short* qb  = (short*)(ws + (size_t)20 * 1024 * 1024);
  short* ctx = (short*)(ws + (size_t)36 * 1024 * 1024);
  short* qhT = xt;   // xt dead after k_gemm<0>

  k_xt<<<dim3(64, 32, 4), 256, 0, stream>>>(x, xt);
  k_cast<<<1024, 256, 0, stream>>>(Wq, wqb, 262144);
  k_cast<<<1024, 256, 0, stream>>>(Wo, wob, 262144);
  k_gemm<0><<<dim3(64, 8), 256, 0, stream>>>(xt, wqb, qb);
  k_qt<<<dim3(32, 16, 4), 256, 0, stream>>>(qb, qhT);
  k_attn<<<dim3(16, 32), 256, 0, stream>>>(qb, qhT, mask, ctx);
  k_gemm<1><<<dim3(8, 64), 256, 0, stream>>>(wob, ctx, d_out);
}

// Round 7
// 164.350 us; speedup vs baseline: 1.8752x; 1.0817x over previous
//
#include <hip/hip_runtime.h>

#define TT 2048
#define DD 1024
#define NHH 8
#define DKK 128
// softmax in log2 domain: v_exp_f32 is natively 2^x
#define SCALE2 0.1275174724f          /* (1/sqrt(128)) * log2(e) */
#define NEG2  -1.4426950409e30f       /* -1e30 * log2(e) */

typedef __attribute__((ext_vector_type(8)))  short short8;
typedef __attribute__((ext_vector_type(4)))  short short4v;
typedef __attribute__((ext_vector_type(4)))  float float4v;
typedef __attribute__((ext_vector_type(16))) float float16v;
typedef __attribute__((ext_vector_type(4)))  int   int4v;

__device__ __forceinline__ short f2bf(float f) {
  union { float f; unsigned u; } v; v.f = f;
  unsigned r = v.u + 0x7FFFu + ((v.u >> 16) & 1u);
  return (short)(r >> 16);
}
__device__ __forceinline__ unsigned cvtpk(float lo, float hi) {
  unsigned r;
  asm("v_cvt_pk_bf16_f32 %0, %1, %2" : "=v"(r) : "v"(lo), "v"(hi));
  return r;
}
// pairwise exchange lane l <-> l^32 (VALU pipe, not LDS)
__device__ __forceinline__ float xhalf_max(float x) {
  float y;
  asm("v_mov_b32 %0, %1" : "=v"(y) : "v"(x));
  asm("v_permlane32_swap_b32 %0, %1" : "+v"(x), "+v"(y));
  return fmaxf(x, y);
}
__device__ __forceinline__ float xhalf_add(float x) {
  float y;
  asm("v_mov_b32 %0, %1" : "=v"(y) : "v"(x));
  asm("v_permlane32_swap_b32 %0, %1" : "+v"(x), "+v"(y));
  return x + y;
}

// ---- transpose + cast: x (B, D, T) f32 -> xt (B*T, D) bf16 ----
__global__ __launch_bounds__(256) void k_xt(const float* __restrict__ x,
                                            short* __restrict__ xt) {
  __shared__ float tile[32][33];
  int b = blockIdx.z, d0 = blockIdx.y << 5, t0 = blockIdx.x << 5;
  int tx = threadIdx.x & 31, ty = threadIdx.x >> 5;
  const float* xp = x + ((size_t)b * DD + d0) * TT + t0;
#pragma unroll
  for (int yy = 0; yy < 32; yy += 8)
    tile[ty + yy][tx] = xp[(size_t)(ty + yy) * TT + tx];
  __syncthreads();
  short* op = xt + ((size_t)b * TT + t0) * DD + d0;
#pragma unroll
  for (int yy = 0; yy < 32; yy += 8)
    op[(size_t)(ty + yy) * DD + tx] = f2bf(tile[tx][ty + yy]);
}

__global__ void k_cast(const float* __restrict__ w, short* __restrict__ o, int n4) {
  int i = blockIdx.x * 256 + threadIdx.x;
  if (i < n4) {
    float4v v = ((const float4v*)w)[i];
    short4v s;
#pragma unroll
    for (int j = 0; j < 4; ++j) s[j] = f2bf(v[j]);
    ((short4v*)o)[i] = s;
  }
}

// ---- transpose Q: qb (B*T, 1024) bf16 -> qhT (B*1024, T) bf16 ----
__global__ __launch_bounds__(256) void k_qt(const short* __restrict__ qb,
                                            short* __restrict__ qhT) {
  __shared__ short tile[64][65];
  int b = blockIdx.z, n0 = blockIdx.y << 6, t0 = blockIdx.x << 6;
  int tx = threadIdx.x & 63, ty = threadIdx.x >> 6;
  const short* ip = qb + ((size_t)(b * TT + t0)) * DD + n0;
#pragma unroll
  for (int yy = 0; yy < 64; yy += 4)
    tile[ty + yy][tx] = ip[(size_t)(ty + yy) * DD + tx];
  __syncthreads();
  short* op = qhT + ((size_t)(b * DD + n0)) * TT + t0;
#pragma unroll
  for (int yy = 0; yy < 64; yy += 4)
    op[(size_t)(ty + yy) * TT + tx] = tile[tx][ty + yy];
}

// ---- GEMM: C = A(M x 1024) * Bt(N x 1024)^T ----
template <int EPI>
__global__ __launch_bounds__(256) void k_gemm(const short* __restrict__ A,
                                              const short* __restrict__ Bt,
                                              void* __restrict__ Cout) {
  __shared__ short As[128][72];
  __shared__ short Bs[128][72];
  const int K = 1024;
  int tm = blockIdx.x * 128, tn = blockIdx.y * 128;
  int tid = threadIdx.x, lane = tid & 63, w = tid >> 6;
  int wm = (w >> 1) * 64, wn = (w & 1) * 64;
  int g = lane >> 4;

  float4v acc[4][4];
#pragma unroll
  for (int mt = 0; mt < 4; ++mt)
#pragma unroll
    for (int nt = 0; nt < 4; ++nt) acc[mt][nt] = (float4v){0.f, 0.f, 0.f, 0.f};

  for (int k0 = 0; k0 < K; k0 += 64) {
    __syncthreads();
#pragma unroll
    for (int c = 0; c < 4; ++c) {
      int chunk = tid + 256 * c;
      int row = chunk >> 3, col8 = chunk & 7;
      int4v va = *(const int4v*)(A + (size_t)(tm + row) * K + k0 + col8 * 8);
      *(int4v*)(&As[row][col8 * 8]) = va;
      int4v vb = *(const int4v*)(Bt + (size_t)(tn + row) * K + k0 + col8 * 8);
      *(int4v*)(&Bs[row][col8 * 8]) = vb;
    }
    __syncthreads();
#pragma unroll
    for (int k4 = 0; k4 < 2; ++k4) {
      int kk = k4 * 32 + g * 8;
      short8 af[4], bfr[4];
#pragma unroll
      for (int mt = 0; mt < 4; ++mt)
        af[mt] = *(const short8*)(&As[wm + mt * 16 + (lane & 15)][kk]);
#pragma unroll
      for (int nt = 0; nt < 4; ++nt)
        bfr[nt] = *(const short8*)(&Bs[wn + nt * 16 + (lane & 15)][kk]);
#pragma unroll
      for (int mt = 0; mt < 4; ++mt)
#pragma unroll
        for (int nt = 0; nt < 4; ++nt)
          acc[mt][nt] = __builtin_amdgcn_mfma_f32_16x16x32_bf16(af[mt], bfr[nt],
                                                                acc[mt][nt], 0, 0, 0);
    }
  }

#pragma unroll
  for (int mt = 0; mt < 4; ++mt)
#pragma unroll
    for (int nt = 0; nt < 4; ++nt)
#pragma unroll
      for (int r = 0; r < 4; ++r) {
        int m = tm + wm + mt * 16 + g * 4 + r;
        int n = tn + wn + nt * 16 + (lane & 15);
        float v = acc[mt][nt][r];
        if (EPI == 0) {
          ((short*)Cout)[(size_t)m * 1024 + n] = f2bf(v);
        } else {
          int b = n >> 11, t = n & 2047;
          ((float*)Cout)[((size_t)b * 1024 + m) * 2048 + t] = v;
        }
      }
}

// ---- fused masked self-attention, flash-style, 32x32 MFMA ----
// grid (T/128, B*NH), block 256 = 4 waves x 32 q-rows. KVBLK=64.
// Swapped QK^T: lane owns q = lane&31 (C cols). Softmax fully per-lane +
// 1 permlane32_swap. P->B-frag via cvt_pk + permlane32_swap (T12).
// PV computes O^T = mfma(V^T-frag, P^T-frag) so O stays q-per-lane.
__global__ __launch_bounds__(256, 2) void k_attn(const short* __restrict__ q,
                                                 const short* __restrict__ qhT,
                                                 const float* __restrict__ mask,
                                                 short* __restrict__ ctx) {
  __shared__ __align__(16) short Ks[64 * 128];   // [key][d], col16 ^= key&7
  __shared__ __align__(16) short Vt[128 * 64];   // [d][key], col16 ^= d&7
  __shared__ __align__(16) float smask[64];

  int qt = blockIdx.x, bh = blockIdx.y;
  int b = bh >> 3, h = bh & 7;
  int tid = threadIdx.x, lane = tid & 63, w = tid >> 6;
  int ql32 = lane & 31, hi = lane >> 5;

  int qrow = qt * 128 + w * 32 + ql32;
  const short* qp = q + ((size_t)(b * TT + qrow)) * DD + h * DKK;
  short8 qf[8];
#pragma unroll
  for (int kc8 = 0; kc8 < 8; ++kc8)
    qf[kc8] = *(const short8*)(qp + kc8 * 16 + hi * 8);
  float rm = mask[(size_t)b * TT + qrow];

  // staging maps
  int oc = tid & 15, r2 = tid >> 4;
  const short* kbase_g = q + ((size_t)b * TT) * DD + h * DKK + oc * 8;
  const short* vbase_g = qhT + ((size_t)(b * DD + h * DKK)) * TT;
  int vd[4], vko[4], vwoff[4];
#pragma unroll
  for (int p = 0; p < 4; ++p) {
    int idx = p * 256 + tid;
    vd[p] = idx >> 3;
    vko[p] = idx & 7;
    vwoff[p] = vd[p] * 64 + ((vko[p] ^ (vd[p] & 7)) * 8);
  }
  int kwoff[2][2];
#pragma unroll
  for (int ps = 0; ps < 2; ++ps) {
    int ra = 2 * r2 + 32 * ps, rb = ra + 1;
    kwoff[ps][0] = ra * 128 + ((oc ^ (ra & 7)) * 8);
    kwoff[ps][1] = rb * 128 + ((oc ^ (rb & 7)) * 8);
  }

  // prologue: tile 0 into regs
  short8 va[2], vb[2], vv[4];
#pragma unroll
  for (int ps = 0; ps < 2; ++ps) {
    const short* kp = kbase_g + (size_t)(2 * r2 + 32 * ps) * DD;
    va[ps] = *(const short8*)(kp);
    vb[ps] = *(const short8*)(kp + DD);
  }
#pragma unroll
  for (int p = 0; p < 4; ++p)
    vv[p] = *(const short8*)(vbase_g + (size_t)vd[p] * TT + vko[p] * 8);
  float mreg = (tid < 64) ? mask[(size_t)b * TT + tid] : 0.f;

  float m_run = -__builtin_inff();
  float l_run = 0.f;
  float16v o[4];
#pragma unroll
  for (int nt = 0; nt < 4; ++nt)
#pragma unroll
    for (int r = 0; r < 16; ++r) o[nt][r] = 0.f;

  for (int kt = 0; kt < 32; ++kt) {
    __syncthreads();
#pragma unroll
    for (int ps = 0; ps < 2; ++ps) {
      *(short8*)(Ks + kwoff[ps][0]) = va[ps];
      *(short8*)(Ks + kwoff[ps][1]) = vb[ps];
    }
#pragma unroll
    for (int p = 0; p < 4; ++p)
      *(short8*)(Vt + vwoff[p]) = vv[p];
    if (tid < 64) smask[tid] = mreg;
    __syncthreads();

    // prefetch next tile into regs
    if (kt < 31) {
      int kb0n = (kt + 1) * 64;
      const short* kpn = kbase_g + (size_t)kb0n * DD;
#pragma unroll
      for (int ps = 0; ps < 2; ++ps) {
        const short* kp = kpn + (size_t)(2 * r2 + 32 * ps) * DD;
        va[ps] = *(const short8*)(kp);
        vb[ps] = *(const short8*)(kp + DD);
      }
#pragma unroll
      for (int p = 0; p < 4; ++p)
        vv[p] = *(const short8*)(vbase_g + (size_t)vd[p] * TT + kb0n + vko[p] * 8);
      if (tid < 64) mreg = mask[(size_t)b * TT + kb0n + tid];
    }

    // ---- S^T = K * Q^T : 2 kb-tiles of 32 keys, C col = q = ql32 ----
    float16v st0, st1;
#pragma unroll
    for (int r = 0; r < 16; ++r) { st0[r] = 0.f; st1[r] = 0.f; }
    __builtin_amdgcn_s_setprio(1);
#pragma unroll
    for (int kc8 = 0; kc8 < 8; ++kc8) {
      int csw = ((kc8 * 2 + hi) ^ (ql32 & 7)) * 8;
      short8 kf0 = *(const short8*)(Ks + ql32 * 128 + csw);
      short8 kf1 = *(const short8*)(Ks + (32 + ql32) * 128 + csw);
      st0 = __builtin_amdgcn_mfma_f32_32x32x16_bf16(kf0, qf[kc8], st0, 0, 0, 0);
      st1 = __builtin_amdgcn_mfma_f32_32x32x16_bf16(kf1, qf[kc8], st1, 0, 0, 0);
    }
    __builtin_amdgcn_s_setprio(0);

    // ---- masked logits (log2) + online softmax, per-lane q-row ----
    // lane reg -> key: kb*32 + (reg&3) + 8*(reg>>2) + 4*hi  (verified C-layout)
    float rowmax = -__builtin_inff();
#pragma unroll
    for (int kb = 0; kb < 2; ++kb) {
#pragma unroll
      for (int a = 0; a < 4; ++a) {
        float4v sm = *(const float4v*)(&smask[kb * 32 + 8 * a + 4 * hi]);
#pragma unroll
        for (int j = 0; j < 4; ++j) {
          float sv = (kb == 0) ? st0[4 * a + j] : st1[4 * a + j];
          float v = (sm[j] != 0.f) ? sv * SCALE2 : NEG2;
          v *= rm;
          if (kb == 0) st0[4 * a + j] = v; else st1[4 * a + j] = v;
          rowmax = fmaxf(rowmax, v);
        }
      }
    }
    rowmax = xhalf_max(rowmax);
    float m_new = fmaxf(m_run, rowmax);
    float fac = __builtin_amdgcn_exp2f(m_run - m_new);
    float tsum = 0.f;
#pragma unroll
    for (int r = 0; r < 16; ++r) {
      float p0 = __builtin_amdgcn_exp2f(st0[r] - m_new);
      float p1 = __builtin_amdgcn_exp2f(st1[r] - m_new);
      st0[r] = p0; st1[r] = p1;
      tsum += p0 + p1;
    }
    tsum = xhalf_add(tsum);
    l_run = l_run * fac + tsum;
    m_run = m_new;
#pragma unroll
    for (int nt = 0; nt < 4; ++nt)
#pragma unroll
      for (int r = 0; r < 16; ++r) o[nt][r] *= fac;

    // ---- P^T B-frags in-register: cvt_pk + permlane32_swap (T12) ----
    short8 pa[4];
#pragma unroll
    for (int kc = 0; kc < 4; ++kc) {
      int a0 = 2 * (kc & 1);
      unsigned x0, x1, y0, y1;
      if (kc < 2) {
        x0 = cvtpk(st0[4 * a0 + 0], st0[4 * a0 + 1]);
        x1 = cvtpk(st0[4 * a0 + 2], st0[4 * a0 + 3]);
        y0 = cvtpk(st0[4 * a0 + 4], st0[4 * a0 + 5]);
        y1 = cvtpk(st0[4 * a0 + 6], st0[4 * a0 + 7]);
      } else {
        x0 = cvtpk(st1[4 * a0 + 0], st1[4 * a0 + 1]);
        x1 = cvtpk(st1[4 * a0 + 2], st1[4 * a0 + 3]);
        y0 = cvtpk(st1[4 * a0 + 4], st1[4 * a0 + 5]);
        y1 = cvtpk(st1[4 * a0 + 6], st1[4 * a0 + 7]);
      }
      asm("v_permlane32_swap_b32 %0, %1" : "+v"(x0), "+v"(y0));
      asm("v_permlane32_swap_b32 %0, %1" : "+v"(x1), "+v"(y1));
      union { unsigned u[4]; short8 s8; } pu;
      pu.u[0] = x0; pu.u[1] = x1; pu.u[2] = y0; pu.u[3] = y1;
      pa[kc] = pu.s8;
    }

    // ---- O^T += V^T * P^T ----
    __builtin_amdgcn_s_setprio(1);
#pragma unroll
    for (int nt = 0; nt < 4; ++nt) {
      int row = nt * 32 + ql32;
#pragma unroll
      for (int kc = 0; kc < 4; ++kc) {
        short8 vf = *(const short8*)(Vt + row * 64 + (((kc * 2 + hi) ^ (ql32 & 7)) * 8));
        o[nt] = __builtin_amdgcn_mfma_f32_32x32x16_bf16(vf, pa[kc], o[nt], 0, 0, 0);
      }
    }
    __builtin_amdgcn_s_setprio(0);
  }

  // ---- normalize and write ctx: lane owns q-row, d = nt*32+8a+4hi+{0..3} ----
  float il = 1.0f / l_run;
  short* cp = ctx + ((size_t)(b * TT + qrow)) * DD + h * DKK;
#pragma unroll
  for (int nt = 0; nt < 4; ++nt)
#pragma unroll
    for (int a = 0; a < 4; ++a) {
      short4v sv;
#pragma unroll
      for (int j = 0; j < 4; ++j) sv[j] = f2bf(o[nt][4 * a + j] * il);
      *(short4v*)(cp + nt * 32 + 8 * a + 4 * hi) = sv;
    }
}

extern "C" void kernel_launch(void* const* d_in, const int* in_sizes, int n_in,
                              void* d_out, int out_size, void* d_ws, size_t ws_size,
                              hipStream_t stream) {
  const float* x    = (const float*)d_in[0];
  const float* mask = (const float*)d_in[1];
  const float* Wq   = (const float*)d_in[2];
  const float* Wo   = (const float*)d_in[3];
  char* ws = (char*)d_ws;
  short* xt  = (short*)(ws);                              // 16 MB (reused as qhT)
  short* wqb = (short*)(ws + (size_t)16 * 1024 * 1024);
  short* wob = (short*)(ws + (size_t)18 * 1024 * 1024);
  short* qb  = (short*)(ws + (size_t)20 * 1024 * 1024);
  short* ctx = (short*)(ws + (size_t)36 * 1024 * 1024);
  short* qhT = xt;   // xt dead after k_gemm<0>

  k_xt<<<dim3(64, 32, 4), 256, 0, stream>>>(x, xt);
  k_cast<<<1024, 256, 0, stream>>>(Wq, wqb, 262144);
  k_cast<<<1024, 256, 0, stream>>>(Wo, wob, 262144);
  k_gemm<0><<<dim3(64, 8), 256, 0, stream>>>(xt, wqb, qb);
  k_qt<<<dim3(32, 16, 4), 256, 0, stream>>>(qb, qhT);
  k_attn<<<dim3(16, 32), 256, 0, stream>>>(qb, qhT, mask, ctx);
  k_gemm<1><<<dim3(8, 64), 256, 0, stream>>>(wob, ctx, d_out);
}